// Round 17
// baseline (203.134 us; speedup 1.0000x reference)
//
#include <hip/hip_runtime.h>

typedef _Float16 half8 __attribute__((ext_vector_type(8)));
typedef __fp16  fp16x2 __attribute__((ext_vector_type(2)));
typedef float f32x4 __attribute__((ext_vector_type(4)));

#define HH 6144
#define WW 6144
#define KH 11
#define KW 11
#define OH (HH - KH + 1)   // 6134
#define OW (WW - KW + 1)   // 6134

#define BROWS 64           // out rows per block (wave wv owns rows 16wv..16wv+15)
#define BCOLS 64           // out cols per block
#define SR 74              // staged input rows (64 + 10 halo)
#define SCH 20             // 16B fp32 chunks per row (80 f32; need 79)
#define F_ROWB 320         // fp32 row bytes (20*16, rows packed linearly)
#define H_ROWB 184         // fp16 row stride (46 dw = 14 mod 32, gcd 2 -> 2-way = free)
#define A_WAVES 24         // 1536 slots >= 1480 real; clamp r>73
#define B_LDS 13616        // 74*184, 16-aligned; B in dead F space [13616,20784)
#define B_BYTES 7168       // 448 slots * 16 B (sigma-permuted)
#define LDSB 24576         // A region 24*1024 -> 6 blocks/CU
#define CV_TASKS 740       // 74 rows * 10 (32B units)

#define TILES_X 96
#define TILES_Y 96
#define NWG (TILES_X * TILES_Y)   // 9216 = 8 * 1152

// ---- prep: compact B table, sigma-PERMUTED slot order (verified r15) ------
// memory slot p = kb*40 + sg; logical s = (sg%5)*8 + sg/5;
// value(kb,s,e) = W[kb][s+e-15] (zero outside [0,11)).
// Kernel reads sigma(s) = (s&7)*5 + (s>>3): the bank-aliasing pair (s, s+8)
// lands in adjacent 16B slots -> distinct bank windows -> conflict-free.
__global__ void build_B_kernel(const float* __restrict__ Wt,
                               _Float16* __restrict__ Bc) {
    const int t = (int)blockIdx.x * 256 + (int)threadIdx.x;
    if (t < 448 * 8) {
        const int e  = t & 7;
        const int p  = t >> 3;
        const int kb = p / 40;
        const int sg = p - kb * 40;
        const int s  = (sg % 5) * 8 + sg / 5;
        float v = 0.f;
        if (kb < KH) {
            const int d = s + e - 15;
            if (d >= 0 && d < KW) v = Wt[kb * KW + d];
        }
        Bc[t] = (_Float16)v;
    }
}

union pk2 { fp16x2 h; unsigned int u; };
static __device__ __forceinline__ unsigned int cvt2(float a, float b) {
#if defined(__has_builtin) && __has_builtin(__builtin_amdgcn_cvt_pkrtz)
    pk2 r; r.h = __builtin_amdgcn_cvt_pkrtz(a, b);
#else
    pk2 r; r.h[0] = (__fp16)a; r.h[1] = (__fp16)b;
#endif
    return r.u;
}

__global__ __launch_bounds__(256, 6)
void conv2d_dma6_kernel(const float* __restrict__ X,
                        const _Float16* __restrict__ Bc,
                        const float* __restrict__ bias,
                        float* __restrict__ out)
{
    __shared__ __align__(16) char lds[LDSB];

    // XCD-chunked remap (bijective: 9216 % 8 == 0)
    const int bid = (int)blockIdx.x;
    const int sb  = (bid & 7) * (NWG / 8) + (bid >> 3);
    const int txt = sb % TILES_X;
    const int tyt = sb / TILES_X;

    const int x0 = txt * BCOLS;
    const int y0 = tyt * BROWS;
    const int tid = (int)threadIdx.x;
    const int lane = tid & 63;
    const int wv = tid >> 6;        // = rt (row-tile 0..3)
    const int n  = lane & 15;
    const int h  = lane >> 4;
    const float bv = bias[0];

    const bool interior = (txt < TILES_X - 1) && (tyt < TILES_Y - 1);

    // ---------------- stage A: DMA global -> LDS (F region, linear) ---------
    // F slot t (t < 1536): X row r = t/20 (clamped), chunk j = t%20.
    if (interior) {
        #pragma unroll
        for (int k = 0; k < 6; ++k) {
            const int wabs = k * 4 + wv;              // 0..23, exactly 6/wave
            char* ldst = lds + wabs * 1024;           // uniform; HW adds lane*16
            const int t = wabs * 64 + lane;
            int r = t / SCH;
            const int j = t - r * SCH;
            if (r > SR - 1) r = SR - 1;               // pad tasks: benign clamp
            const void* src = (const void*)(X + (size_t)(y0 + r) * WW + (x0 + 4 * j));
            __builtin_amdgcn_global_load_lds(
                (const __attribute__((address_space(1))) void*)src,
                (__attribute__((address_space(3))) void*)ldst,
                16, 0, 0);
        }
    } else {
        #pragma unroll 1
        for (int k = 0; k < 6; ++k) {
            const int wabs = k * 4 + wv;
            const int t = wabs * 64 + lane;
            int r = t / SCH;
            const int j = t - r * SCH;
            if (r > SR - 1) r = SR - 1;
            const int gy = y0 + r;
            const int gx = x0 + 4 * j;
            f32x4 v = {0.f, 0.f, 0.f, 0.f};
            if (gy < HH) {
                const float* rp = X + (size_t)gy * WW;
                if (gx + 3 < WW) {
                    v = *reinterpret_cast<const f32x4*>(rp + gx);
                } else {
                    if (gx + 0 < WW) v[0] = rp[gx + 0];
                    if (gx + 1 < WW) v[1] = rp[gx + 1];
                    if (gx + 2 < WW) v[2] = rp[gx + 2];
                }
            }
            *reinterpret_cast<f32x4*>(lds + (size_t)t * 16) = v;
        }
    }

    __syncthreads();   // drains A-DMA (vmcnt(0))

    // ---------------- convert pass: fp32 F (320-stride) -> regs -------------
    // task idx: r = idx/10, m = idx%10 (32B = 8 f32 cols each)
    f32x4 CV[3][2];
    #pragma unroll
    for (int it = 0; it < 3; ++it) {
        const int idx = it * 256 + tid;
        if (idx < CV_TASKS) {
            const int r = idx / 10;
            const int m = idx - r * 10;
            const char* frow = lds + (size_t)r * F_ROWB + m * 32;
            CV[it][0] = *reinterpret_cast<const f32x4*>(frow);
            CV[it][1] = *reinterpret_cast<const f32x4*>(frow + 16);
        }
    }

    __syncthreads();   // ALL F reads done -> F region dead, reusable

    // ---- stage B: DMA weight table into dead F space [B_LDS, B_LDS+7168) ---
    if (interior) {
        #pragma unroll
        for (int k = 0; k < 2; ++k) {
            const int wb = k * 4 + wv;
            if (wb < 7) {
                char* ldst = lds + B_LDS + wb * 1024;
                const void* src = (const void*)((const char*)Bc + (size_t)(wb * 64 + lane) * 16);
                __builtin_amdgcn_global_load_lds(
                    (const __attribute__((address_space(1))) void*)src,
                    (__attribute__((address_space(3))) void*)ldst,
                    16, 0, 0);
            }
        }
    } else {
        #pragma unroll
        for (int k = 0; k < 2; ++k) {
            const int wb = k * 4 + wv;
            if (wb < 7) {
                const int t = wb * 64 + lane;
                *reinterpret_cast<uint4*>(lds + B_LDS + (size_t)t * 16) =
                    *reinterpret_cast<const uint4*>((const char*)Bc + (size_t)t * 16);
            }
        }
    }

    // ---- write H rows (stride 184) into [0, 13616) -------------------------
    #pragma unroll
    for (int it = 0; it < 3; ++it) {
        const int idx = it * 256 + tid;
        if (idx < CV_TASKS) {
            const int r = idx / 10;
            const int m = idx - r * 10;
            union { unsigned int u[4]; uint4 q; } fr;
            fr.u[0] = cvt2(CV[it][0][0], CV[it][0][1]);
            fr.u[1] = cvt2(CV[it][0][2], CV[it][0][3]);
            fr.u[2] = cvt2(CV[it][1][0], CV[it][1][1]);
            fr.u[3] = cvt2(CV[it][1][2], CV[it][1][3]);
            *reinterpret_cast<uint4*>(lds + (size_t)r * H_ROWB + m * 16) = fr.q;
        }
    }

    f32x4 acc[4];
    #pragma unroll
    for (int c = 0; c < 4; ++c) acc[c] = (f32x4){bv, bv, bv, bv};

    __syncthreads();   // drains B-DMA + orders H writes

    // ---------------- compute: one b128 per MFMA (fp16) ---------------------
    // A(kb,c) lane(n,h): row 16wv+n+kb, addr = row*184 + 32c + 16h
    // B(kb)   lane(n,h): addr = B_LDS + sigma(8h-n+15)*16 + kb*640
    const int s_log = 8 * h - n + 15;
    const int sig   = (s_log & 7) * 5 + (s_log >> 3);
    const char* abase = lds + (16 * wv + n) * H_ROWB + 16 * h;
    const char* bbase = lds + B_LDS + sig * 16;
    #pragma unroll
    for (int kb = 0; kb < 11; ++kb) {
        const half8 bf = *reinterpret_cast<const half8*>(bbase + kb * 640);
        const char* arow = abase + kb * H_ROWB;
        #pragma unroll
        for (int c = 0; c < 4; ++c) {
            half8 a = *reinterpret_cast<const half8*>(arow + 32 * c);
            acc[c] = __builtin_amdgcn_mfma_f32_16x16x32_f16(a, bf, acc[c], 0, 0, 0);
        }
    }

    // ---------------- store: out row y0+16wv+4h+r, col x0+16c+n -------------
    const int orow0 = y0 + 16 * wv + 4 * h;
    const int ocol0 = x0 + n;
    if (interior) {
        #pragma unroll
        for (int r = 0; r < 4; ++r) {
            float* op = out + (size_t)(orow0 + r) * OW + ocol0;
            #pragma unroll
            for (int c = 0; c < 4; ++c)
                op[16 * c] = acc[c][r];
        }
    } else {
        #pragma unroll
        for (int r = 0; r < 4; ++r) {
            if (orow0 + r < OH) {
                float* op = out + (size_t)(orow0 + r) * OW + ocol0;
                #pragma unroll
                for (int c = 0; c < 4; ++c)
                    if (ocol0 + 16 * c < OW) op[16 * c] = acc[c][r];
            }
        }
    }
}

extern "C" void kernel_launch(void* const* d_in, const int* in_sizes, int n_in,
                              void* d_out, int out_size, void* d_ws, size_t ws_size,
                              hipStream_t stream) {
    const float* X    = (const float*)d_in[0];
    const float* Wt   = (const float*)d_in[1];
    const float* bias = (const float*)d_in[2];
    float* out        = (float*)d_out;
    _Float16* Bc      = (_Float16*)d_ws;      // 7168 B

    build_B_kernel<<<dim3(14), dim3(256), 0, stream>>>(Wt, Bc);
    conv2d_dma6_kernel<<<dim3(NWG), dim3(256), 0, stream>>>(X, Bc, bias, out);
}

// Round 18
// 86.608 us; speedup vs baseline: 2.3454x; 2.3454x over previous
//
#include <hip/hip_runtime.h>

typedef _Float16 half8 __attribute__((ext_vector_type(8)));
typedef __fp16  fp16x2 __attribute__((ext_vector_type(2)));
typedef float f32x4 __attribute__((ext_vector_type(4)));

#define HH 6144
#define WW 6144
#define KH 11
#define KW 11
#define OH (HH - KH + 1)   // 6134
#define OW (WW - KW + 1)   // 6134

#define BROWS 32           // out rows per tile
#define BCOLS 96           // out cols per tile
#define SR 42              // staged input rows per tile
#define SCH 28             // 16B fp32 chunks per row (112 f32; need 111)
#define F_ROWB 448         // fp32 row bytes
#define H_ROWB 224         // fp16 row bytes (verified dma5 layout)
#define FBUF 19456         // 19 DMA wave-chunks of 1024 B
#define B_LDS 38912        // 2*FBUF
#define B_BYTES 7168
#define LDSB 46080         // 2 F buffers + B -> 3 blocks/CU
#define CV_TASKS 588       // 42 rows * 14 uint4
#define NT 4               // tiles per block, stacked vertically

#define TILES_X 64
#define STRIPES 48
#define NWG (TILES_X * STRIPES)   // 3072 = 8 * 384

// ---- prep: compact B table (verified rounds 12-15) ------------------------
// slot (kb*40+s), elem e: value W[kb][s+e-15] (zero outside [0,11))
__global__ void build_B_kernel(const float* __restrict__ Wt,
                               _Float16* __restrict__ Bc) {
    const int t = (int)blockIdx.x * 256 + (int)threadIdx.x;
    if (t < 448 * 8) {
        const int e    = t & 7;
        const int slot = t >> 3;
        const int kb   = slot / 40;
        const int s    = slot - kb * 40;
        float v = 0.f;
        if (kb < KH) {
            const int d = s + e - 15;
            if (d >= 0 && d < KW) v = Wt[kb * KW + d];
        }
        Bc[t] = (_Float16)v;
    }
}

union pk2 { fp16x2 h; unsigned int u; };
static __device__ __forceinline__ unsigned int cvt2(float a, float b) {
#if defined(__has_builtin) && __has_builtin(__builtin_amdgcn_cvt_pkrtz)
    pk2 r; r.h = __builtin_amdgcn_cvt_pkrtz(a, b);
#else
    pk2 r; r.h[0] = (__fp16)a; r.h[1] = (__fp16)b;
#endif
    return r.u;
}

#define DMA16(srcp, dstp) \
    __builtin_amdgcn_global_load_lds( \
        (const __attribute__((address_space(1))) void*)(srcp), \
        (__attribute__((address_space(3))) void*)(dstp), 16, 0, 0)

__global__ __launch_bounds__(256, 3)
void conv2d_pipe_kernel(const float* __restrict__ X,
                        const _Float16* __restrict__ Bc,
                        const float* __restrict__ bias,
                        float* __restrict__ out)
{
    __shared__ __align__(16) char lds[LDSB];

    // XCD-chunked remap (bijective: 3072 % 8 == 0)
    const int bid = (int)blockIdx.x;
    const int sb  = (bid & 7) * (NWG / 8) + (bid >> 3);
    const int txt = sb % TILES_X;
    const int stp = sb / TILES_X;

    const int x0 = txt * BCOLS;
    const int yb = stp * (NT * BROWS);
    const int tid = (int)threadIdx.x;
    const int lane = tid & 63;
    const int wv = tid >> 6;
    const int n  = lane & 15;
    const int h  = lane >> 4;
    const int rt = wv & 1;
    const int cs = wv >> 1;
    const float bv = bias[0];

    const bool interior = (txt < TILES_X - 1) && (stp < STRIPES - 1);

    // per-thread DMA task coords (same every tile): wabs = k*4+wv, t = wabs*64+lane
    int dr[5], dj[5];
    #pragma unroll
    for (int k = 0; k < 5; ++k) {
        const int wabs = k * 4 + wv;
        const int t = wabs * 64 + lane;
        int r = t / SCH;
        dj[k] = t - r * SCH;
        dr[k] = (r > SR - 1) ? (SR - 1) : r;     // pad clamp
    }

    if (interior) {
        // ---------------- prologue: B-DMA + F[0]-DMA, one full drain --------
        #pragma unroll
        for (int k = 0; k < 2; ++k) {
            const int wb = k * 4 + wv;
            if (wb < 7)
                DMA16((const char*)Bc + (size_t)(wb * 64 + lane) * 16,
                      lds + B_LDS + wb * 1024);
        }
        #pragma unroll
        for (int k = 0; k < 5; ++k) {
            const int wabs = k * 4 + wv;
            if (wabs < 19)
                DMA16(X + (size_t)(yb + dr[k]) * WW + (x0 + 4 * dj[k]),
                      lds + wabs * 1024);
        }
        asm volatile("s_waitcnt vmcnt(0)" ::: "memory");
        __builtin_amdgcn_sched_barrier(0);
        __builtin_amdgcn_s_barrier();

        #pragma unroll
        for (int t4 = 0; t4 < NT; ++t4) {
            char* F = lds + (t4 & 1) * FBUF;
            const int y0 = yb + t4 * BROWS;

            // ---- CV: read fp32 F into regs --------------------------------
            f32x4 CV[3][2];
            #pragma unroll
            for (int it = 0; it < 3; ++it) {
                const int idx = it * 256 + tid;
                if (idx < CV_TASKS) {
                    const int r = idx / 14;
                    const int m = idx - r * 14;
                    const char* frow = F + (size_t)r * F_ROWB + m * 32;
                    CV[it][0] = *reinterpret_cast<const f32x4*>(frow);
                    CV[it][1] = *reinterpret_cast<const f32x4*>(frow + 16);
                }
            }
            asm volatile("s_waitcnt lgkmcnt(0)" ::: "memory");
            __builtin_amdgcn_sched_barrier(0);
            __builtin_amdgcn_s_barrier();          // F[b] fully read -> dead

            // ---- issue NEXT tile's DMA into the other buffer --------------
            if (t4 < NT - 1) {
                char* Fn = lds + ((t4 & 1) ^ 1) * FBUF;
                const int y1 = y0 + BROWS;
                #pragma unroll
                for (int k = 0; k < 5; ++k) {
                    const int wabs = k * 4 + wv;
                    if (wabs < 19)
                        DMA16(X + (size_t)(y1 + dr[k]) * WW + (x0 + 4 * dj[k]),
                              Fn + wabs * 1024);
                }
            }
            __builtin_amdgcn_sched_barrier(0);

            // ---- H-write (fp16, stride 224) into F[b] region --------------
            #pragma unroll
            for (int it = 0; it < 3; ++it) {
                const int idx = it * 256 + tid;
                if (idx < CV_TASKS) {
                    const int r = idx / 14;
                    const int m = idx - r * 14;
                    union { unsigned int u[4]; uint4 q; } fr;
                    fr.u[0] = cvt2(CV[it][0][0], CV[it][0][1]);
                    fr.u[1] = cvt2(CV[it][0][2], CV[it][0][3]);
                    fr.u[2] = cvt2(CV[it][1][0], CV[it][1][1]);
                    fr.u[3] = cvt2(CV[it][1][2], CV[it][1][3]);
                    *reinterpret_cast<uint4*>(F + (size_t)r * H_ROWB + m * 16) = fr.q;
                }
            }

            f32x4 acc[3];
            #pragma unroll
            for (int c = 0; c < 3; ++c) acc[c] = (f32x4){bv, bv, bv, bv};

            asm volatile("s_waitcnt lgkmcnt(0)" ::: "memory");
            __builtin_amdgcn_sched_barrier(0);
            __builtin_amdgcn_s_barrier();          // H visible to all waves

            // ---- compute: verified dma5 fragment mapping ------------------
            const char* abase = F + (16 * rt + n) * H_ROWB + 96 * cs + 16 * h;
            const char* bbase = lds + B_LDS + (8 * h - n + 15) * 16;
            #pragma unroll
            for (int kb = 0; kb < 11; ++kb) {
                const half8 bf = *reinterpret_cast<const half8*>(bbase + kb * 640);
                const char* arow = abase + kb * H_ROWB;
                #pragma unroll
                for (int c = 0; c < 3; ++c) {
                    half8 a = *reinterpret_cast<const half8*>(arow + 32 * c);
                    acc[c] = __builtin_amdgcn_mfma_f32_16x16x32_f16(a, bf, acc[c], 0, 0, 0);
                }
            }

            // ---- store (12 per thread, AFTER the DMA issue) ---------------
            const int orow0 = y0 + 16 * rt + 4 * h;
            const int ocol0 = x0 + 48 * cs + n;
            #pragma unroll
            for (int r = 0; r < 4; ++r) {
                float* op = out + (size_t)(orow0 + r) * OW + ocol0;
                #pragma unroll
                for (int c = 0; c < 3; ++c)
                    op[16 * c] = acc[c][r];
            }

            // ---- counted wait: retire next tile's DMAs, not the stores ----
            if (t4 < NT - 1) {
                asm volatile("s_waitcnt vmcnt(12)" ::: "memory");
                __builtin_amdgcn_sched_barrier(0);
                __builtin_amdgcn_s_barrier();
            }
        }
    } else {
        // ---------------- edge path: full-sync per tile, guarded ------------
        #pragma unroll
        for (int k = 0; k < 2; ++k) {
            const int wb = k * 4 + wv;
            if (wb < 7) {
                const int t = wb * 64 + lane;
                *reinterpret_cast<uint4*>(lds + B_LDS + (size_t)t * 16) =
                    *reinterpret_cast<const uint4*>((const char*)Bc + (size_t)t * 16);
            }
        }
        #pragma unroll 1
        for (int t4 = 0; t4 < NT; ++t4) {
            char* F = lds;                        // single buffer
            const int y0 = yb + t4 * BROWS;
            #pragma unroll 1
            for (int k = 0; k < 5; ++k) {
                const int wabs = k * 4 + wv;
                if (wabs < 19) {
                    const int t = wabs * 64 + lane;
                    const int gy = y0 + dr[k];
                    const int gx = x0 + 4 * dj[k];
                    f32x4 v = {0.f, 0.f, 0.f, 0.f};
                    if (gy < HH) {
                        const float* rp = X + (size_t)gy * WW;
                        if (gx + 3 < WW) {
                            v = *reinterpret_cast<const f32x4*>(rp + gx);
                        } else {
                            if (gx + 0 < WW) v[0] = rp[gx + 0];
                            if (gx + 1 < WW) v[1] = rp[gx + 1];
                            if (gx + 2 < WW) v[2] = rp[gx + 2];
                        }
                    }
                    *reinterpret_cast<f32x4*>(F + (size_t)t * 16) = v;
                }
            }
            __syncthreads();

            f32x4 CV[3][2];
            #pragma unroll
            for (int it = 0; it < 3; ++it) {
                const int idx = it * 256 + tid;
                if (idx < CV_TASKS) {
                    const int r = idx / 14;
                    const int m = idx - r * 14;
                    const char* frow = F + (size_t)r * F_ROWB + m * 32;
                    CV[it][0] = *reinterpret_cast<const f32x4*>(frow);
                    CV[it][1] = *reinterpret_cast<const f32x4*>(frow + 16);
                }
            }
            __syncthreads();

            #pragma unroll
            for (int it = 0; it < 3; ++it) {
                const int idx = it * 256 + tid;
                if (idx < CV_TASKS) {
                    const int r = idx / 14;
                    const int m = idx - r * 14;
                    union { unsigned int u[4]; uint4 q; } fr;
                    fr.u[0] = cvt2(CV[it][0][0], CV[it][0][1]);
                    fr.u[1] = cvt2(CV[it][0][2], CV[it][0][3]);
                    fr.u[2] = cvt2(CV[it][1][0], CV[it][1][1]);
                    fr.u[3] = cvt2(CV[it][1][2], CV[it][1][3]);
                    *reinterpret_cast<uint4*>(F + (size_t)r * H_ROWB + m * 16) = fr.q;
                }
            }

            f32x4 acc[3];
            #pragma unroll
            for (int c = 0; c < 3; ++c) acc[c] = (f32x4){bv, bv, bv, bv};

            __syncthreads();

            const char* abase = F + (16 * rt + n) * H_ROWB + 96 * cs + 16 * h;
            const char* bbase = lds + B_LDS + (8 * h - n + 15) * 16;
            #pragma unroll
            for (int kb = 0; kb < 11; ++kb) {
                const half8 bf = *reinterpret_cast<const half8*>(bbase + kb * 640);
                const char* arow = abase + kb * H_ROWB;
                #pragma unroll
                for (int c = 0; c < 3; ++c) {
                    half8 a = *reinterpret_cast<const half8*>(arow + 32 * c);
                    acc[c] = __builtin_amdgcn_mfma_f32_16x16x32_f16(a, bf, acc[c], 0, 0, 0);
                }
            }

            const int orow0 = y0 + 16 * rt + 4 * h;
            const int ocol0 = x0 + 48 * cs + n;
            #pragma unroll
            for (int r = 0; r < 4; ++r) {
                if (orow0 + r < OH) {
                    float* op = out + (size_t)(orow0 + r) * OW + ocol0;
                    #pragma unroll
                    for (int c = 0; c < 3; ++c)
                        if (ocol0 + 16 * c < OW) op[16 * c] = acc[c][r];
                }
            }
            __syncthreads();   // before next tile overwrites F
        }
    }
}

extern "C" void kernel_launch(void* const* d_in, const int* in_sizes, int n_in,
                              void* d_out, int out_size, void* d_ws, size_t ws_size,
                              hipStream_t stream) {
    const float* X    = (const float*)d_in[0];
    const float* Wt   = (const float*)d_in[1];
    const float* bias = (const float*)d_in[2];
    float* out        = (float*)d_out;
    _Float16* Bc      = (_Float16*)d_ws;      // 7168 B

    build_B_kernel<<<dim3(14), dim3(256), 0, stream>>>(Wt, Bc);
    conv2d_pipe_kernel<<<dim3(NWG), dim3(256), 0, stream>>>(X, Bc, bias, out);
}